// Round 1
// baseline (482.669 us; speedup 1.0000x reference)
//
#include <hip/hip_runtime.h>
#include <hip/hip_bf16.h>

// ---------------- problem constants ----------------
constexpr int Bc  = 4;
constexpr int Sc  = 1024;
constexpr int Hc  = 1536;
constexpr int NHc = 24;
constexpr int DHc = 64;
constexpr int P2c = 512;            // 2*ATT_SPAN
constexpr int MX  = Bc * Sc;        // 4096 rows of X
constexpr int MA  = MX + P2c;       // 4608 rows of [X ; rel_emb]
constexpr int N3  = 3 * Hc;         // 4608 output cols (q|k|v)
constexpr float INV_SCALE = 0.07216878364870323f;  // 1/sqrt(64*3)

using f32x4  = __attribute__((ext_vector_type(4))) float;
using bf16x8 = __attribute__((ext_vector_type(8))) short;
using i32x4  = __attribute__((ext_vector_type(4))) int;
using u16x8  = __attribute__((ext_vector_type(8))) unsigned short;
using u16x4  = __attribute__((ext_vector_type(4))) unsigned short;
typedef unsigned short u16;

#define DEV __device__ __forceinline__

DEV float bf2f(u16 u) { return __uint_as_float(((unsigned)u) << 16); }
DEV u16   f2bf(float f) { return __builtin_bit_cast(unsigned short, __float2bfloat16(f)); }

#if defined(__has_builtin)
#if __has_builtin(__builtin_amdgcn_global_load_lds)
#define HAVE_GLL 1
#endif
#endif
#ifndef HAVE_GLL
#define HAVE_GLL 0
#endif

// Stage 32 rows x 64 bf16 cols of a row-major (stride ldk) global tile into LDS.
// LDS layout: row-major [row][64], with 16B slots XOR-swizzled by (row&7).
// Wave-cooperative: call with per-wave lds base & global base.
DEV void stage32(u16* lds, const u16* g, int ldk, int lane) {
#pragma unroll
  for (int c = 0; c < 4; ++c) {
    const int row   = c * 8 + (lane >> 3);
    const int gslot = (lane & 7) ^ (row & 7);          // pre-swizzled source (rule 21)
    const u16* gp = g + (size_t)row * ldk + gslot * 8;
#if HAVE_GLL
    __builtin_amdgcn_global_load_lds(
        (const __attribute__((address_space(1))) void*)gp,
        (__attribute__((address_space(3))) void*)(lds + c * 8 * 64),
        16, 0, 0);
#else
    i32x4 v = *(const i32x4*)gp;
    *(i32x4*)(lds + row * 64 + (lane & 7) * 8) = v;
#endif
  }
}

DEV bf16x8 ldsFrag(const u16* base, int row, int kh, int lhi) {
  const int idx = row * 64 + ((kh * 32 + lhi * 8) ^ ((row & 7) * 8));
  return *(const bf16x8*)(base + idx);
}

// ---------------- GEMM: C[M,N] = A[M,K=1536] @ Bt[N,K]^T  (+ epilogue) ----------------
// MODE 0: out = bf16( (acc + bias[n]) * (n<1536 ? 1/sqrt(192) : 1) )  (QKV+pos proj)
// MODE 1: out = f32( acc + bias[n] + resid[m,n] )                      (out proj + residual)
template <int MODE>
__global__ __launch_bounds__(256) void gemm128(
    const u16* __restrict__ A, const u16* __restrict__ Bt,
    const float* __restrict__ bias, const float* __restrict__ resid,
    u16* __restrict__ outb, float* __restrict__ outf, int ldo)
{
  __shared__ alignas(16) u16 As[128 * 64];
  __shared__ alignas(16) u16 Bs[128 * 64];
  const int tid = threadIdx.x, wid = tid >> 6, lane = tid & 63;
  const int wr = wid >> 1, wc = wid & 1;
  const int l15 = lane & 15, lhi = lane >> 4;
  const int m0 = blockIdx.y * 128, n0 = blockIdx.x * 128;

  f32x4 acc[4][4] = {};
#pragma unroll 1
  for (int kt = 0; kt < 24; ++kt) {
    const int k0 = kt * 64;
    stage32(As + wid * (32 * 64), A  + (size_t)(m0 + wid * 32) * 1536 + k0, 1536, lane);
    stage32(Bs + wid * (32 * 64), Bt + (size_t)(n0 + wid * 32) * 1536 + k0, 1536, lane);
    asm volatile("s_waitcnt vmcnt(0)" ::: "memory");
    __syncthreads();
#pragma unroll
    for (int kh = 0; kh < 2; ++kh) {
      bf16x8 af[4], bfv[4];
#pragma unroll
      for (int mt = 0; mt < 4; ++mt) af[mt]  = ldsFrag(As, wr * 64 + mt * 16 + l15, kh, lhi);
#pragma unroll
      for (int nt = 0; nt < 4; ++nt) bfv[nt] = ldsFrag(Bs, wc * 64 + nt * 16 + l15, kh, lhi);
#pragma unroll
      for (int mt = 0; mt < 4; ++mt)
#pragma unroll
        for (int nt = 0; nt < 4; ++nt)
          acc[mt][nt] = __builtin_amdgcn_mfma_f32_16x16x32_bf16(af[mt], bfv[nt], acc[mt][nt], 0, 0, 0);
    }
    __syncthreads();
  }
#pragma unroll
  for (int mt = 0; mt < 4; ++mt)
#pragma unroll
    for (int nt = 0; nt < 4; ++nt) {
      const int gn = n0 + wc * 64 + nt * 16 + l15;
      const float bs = bias[gn];
#pragma unroll
      for (int r = 0; r < 4; ++r) {
        const int gm = m0 + wr * 64 + mt * 16 + lhi * 4 + r;
        float v = acc[mt][nt][r] + bs;
        if (MODE == 0) {
          if (gn < Hc) v *= INV_SCALE;
          outb[(size_t)gm * ldo + gn] = f2bf(v);
        } else {
          v += resid[(size_t)gm * ldo + gn];
          outf[(size_t)gm * ldo + gn] = v;
        }
      }
    }
}

// ---------------- prep: bias concat, valid vector, delta->index tables ----------------
__global__ __launch_bounds__(256) void prep_misc(
    const float* __restrict__ bq, const float* __restrict__ bk, const float* __restrict__ bv,
    const int* __restrict__ am, const int* __restrict__ rp,
    float* __restrict__ bias, int* __restrict__ valid,
    u16* __restrict__ cidx, u16* __restrict__ pidx)
{
  const int TOT = N3 + MX + 2047 + 2047;
  for (int i = blockIdx.x * 256 + threadIdx.x; i < TOT; i += gridDim.x * 256) {
    if (i < N3) {
      bias[i] = i < Hc ? bq[i] : (i < 2 * Hc ? bk[i - Hc] : bv[i - 2 * Hc]);
    } else if (i < N3 + MX) {
      const int j = i - N3, b = j >> 10, s = j & 1023;
      valid[j] = am[(size_t)b * Sc * Sc + (size_t)s * Sc + s];   // mask diagonal = valid_i
    } else if (i < N3 + MX + 2047) {
      const int t = i - (N3 + MX), d = t - 1023;                 // delta = q - k
      int v = (d >= 0 ? rp[(size_t)d * Sc] : rp[-d]) + 256;      // clip(bucket(d)+256)
      v = v < 0 ? 0 : (v > 511 ? 511 : v);
      cidx[t] = (u16)v;
    } else {
      const int t = i - (N3 + MX + 2047), d = t - 1023, nd = -d;
      int v = 256 - (nd >= 0 ? rp[(size_t)nd * Sc] : rp[d]);     // clip(-bucket(k-q)+256)
      v = v < 0 ? 0 : (v > 511 ? 511 : v);
      pidx[t] = (u16)v;
    }
  }
}

// ---------------- cast [X ; rel_emb] -> bf16 A-matrix ----------------
__global__ __launch_bounds__(256) void cast_x(const float* __restrict__ hs,
                                              const float* __restrict__ rel,
                                              u16* __restrict__ A)
{
  const size_t total = (size_t)MA * Hc / 4;
  for (size_t i = (size_t)blockIdx.x * 256 + threadIdx.x; i < total; i += (size_t)gridDim.x * 256) {
    const size_t e = i * 4;
    const int row = (int)(e / Hc), col = (int)(e % Hc);
    const float* s = row < MX ? hs + (size_t)row * Hc + col : rel + (size_t)(row - MX) * Hc + col;
    f32x4 v = *(const f32x4*)s;
    u16x4 o = { f2bf(v[0]), f2bf(v[1]), f2bf(v[2]), f2bf(v[3]) };
    *(u16x4*)(A + e) = o;
  }
}

// ---------------- transpose-cast weights: WT[n][k] = W[k][n] (bf16) ----------------
__global__ void transpose_cast(const float* __restrict__ Wq, const float* __restrict__ Wk,
                               const float* __restrict__ Wv, const float* __restrict__ Wo,
                               u16* __restrict__ WT, u16* __restrict__ WOT)
{
  const int z = blockIdx.z;
  const float* src = z == 0 ? Wq : z == 1 ? Wk : z == 2 ? Wv : Wo;
  u16* dst = z == 3 ? WOT : WT + (size_t)z * Hc * Hc;
  __shared__ float t[32][33];
  const int tx = threadIdx.x, ty = threadIdx.y;
  const int kb = blockIdx.y * 32, nb = blockIdx.x * 32;
#pragma unroll
  for (int i = 0; i < 4; ++i)
    t[ty + i * 8][tx] = src[(size_t)(kb + ty + i * 8) * Hc + nb + tx];
  __syncthreads();
#pragma unroll
  for (int i = 0; i < 4; ++i)
    dst[(size_t)(nb + ty + i * 8) * Hc + kb + tx] = f2bf(t[tx][ty + i * 8]);
}

// ---------------- c2p/p2c: per-(b,h) [1024 x 512] = rows @ pos_rows^T (K=64) ----------------
__global__ __launch_bounds__(256) void relmat_kernel(const u16* __restrict__ QKVP,
    u16* __restrict__ c2p, u16* __restrict__ p2c, int bh_base)
{
  const int z = blockIdx.z, lbh = z >> 1, var = z & 1;
  const int bh = bh_base + lbh, b = bh / NHc, h = bh % NHc;
  const int acol = var ? Hc : 0;          // var0: q_s rows, var1: k rows
  const int bcol = var ? 0 : Hc;          // var0: pos_k, var1: pos_q_s
  u16* out = (var ? p2c : c2p) + (size_t)lbh * (Sc * (size_t)P2c);
  const int p0 = blockIdx.x * 128, q0 = blockIdx.y * 64;
  const int tid = threadIdx.x, wid = tid >> 6, lane = tid & 63;
  const int wr = wid >> 1, wc = wid & 1;
  const int l15 = lane & 15, lhi = lane >> 4;

  f32x4 acc[2][4] = {};
#pragma unroll
  for (int kh = 0; kh < 2; ++kh) {
    bf16x8 a[2], bb[4];
#pragma unroll
    for (int mt = 0; mt < 2; ++mt)
      a[mt] = *(const bf16x8*)(QKVP + (size_t)(b * Sc + q0 + wr * 32 + mt * 16 + l15) * 4608
                               + acol + h * 64 + kh * 32 + lhi * 8);
#pragma unroll
    for (int nt = 0; nt < 4; ++nt)
      bb[nt] = *(const bf16x8*)(QKVP + (size_t)(MX + p0 + wc * 64 + nt * 16 + l15) * 4608
                                + bcol + h * 64 + kh * 32 + lhi * 8);
#pragma unroll
    for (int mt = 0; mt < 2; ++mt)
#pragma unroll
      for (int nt = 0; nt < 4; ++nt)
        acc[mt][nt] = __builtin_amdgcn_mfma_f32_16x16x32_bf16(a[mt], bb[nt], acc[mt][nt], 0, 0, 0);
  }
#pragma unroll
  for (int mt = 0; mt < 2; ++mt)
#pragma unroll
    for (int nt = 0; nt < 4; ++nt)
#pragma unroll
      for (int r = 0; r < 4; ++r) {
        const int q = q0 + wr * 32 + mt * 16 + lhi * 4 + r;
        const int p = p0 + wc * 64 + nt * 16 + l15;
        out[(size_t)q * P2c + p] = f2bf(acc[mt][nt][r]);
      }
}

// ---------------- flash attention: 64 q-rows/block, online softmax ----------------
__global__ __launch_bounds__(256) void flash_kernel(
    const u16* __restrict__ QKVP, const u16* __restrict__ c2p, const u16* __restrict__ p2c,
    const int* __restrict__ valid, const u16* __restrict__ cidxG, const u16* __restrict__ pidxG,
    u16* __restrict__ ctx, int bh_base, int chunkBH)
{
  const int id = blockIdx.x;
  const int lbh = id % chunkBH, qi = id / chunkBH;   // same-bh blocks land on one XCD when chunkBH%8==0
  const int bh = bh_base + lbh, b = bh / NHc, h = bh % NHc;
  const int q0 = qi * 64;
  const int tid = threadIdx.x, wid = tid >> 6, lane = tid & 63;
  const int qrb = q0 + wid * 16;
  const int l15 = lane & 15, lhi = lane >> 4;

  __shared__ u16 cT[2047];
  __shared__ u16 pT[2047];
  __shared__ alignas(16) u16 Vt[64 * 64];        // V^T, XOR-swizzled rows (G4)
  __shared__ alignas(16) u16 Pl[4][16 * 64];     // per-wave P strip, swizzled

  for (int i = tid; i < 2047; i += 256) { cT[i] = cidxG[i]; pT[i] = pidxG[i]; }

  bf16x8 aq[2];
#pragma unroll
  for (int kh = 0; kh < 2; ++kh)
    aq[kh] = *(const bf16x8*)(QKVP + (size_t)(b * Sc + qrb + l15) * 4608 + h * 64 + kh * 32 + lhi * 8);

  f32x4 o_acc[4] = {};
  float m_run[4], l_run[4];
#pragma unroll
  for (int r = 0; r < 4; ++r) { m_run[r] = -1e30f; l_run[r] = 0.f; }

  const u16* c2pB = c2p + (size_t)lbh * (Sc * (size_t)P2c);
  const u16* p2cB = p2c + (size_t)lbh * (Sc * (size_t)P2c);
  const int* vb = valid + b * Sc;

  __syncthreads();

  for (int kt = 0; kt < 16; ++kt) {
    const int k0 = kt * 64;
    if (!vb[k0]) break;                           // validity is a prefix
    { // stage V^T into LDS (swizzled)
      const int kr = tid >> 2, d0 = (tid & 3) * 16;
      const u16* vs = QKVP + (size_t)(b * Sc + k0 + kr) * 4608 + 2 * Hc + h * 64 + d0;
      u16x8 x0 = *(const u16x8*)vs;
      u16x8 x1 = *(const u16x8*)(vs + 8);
#pragma unroll
      for (int i = 0; i < 8; ++i) { const int d = d0 + i;     Vt[d * 64 + (kr ^ ((d & 7) * 8))] = x0[i]; }
#pragma unroll
      for (int i = 0; i < 8; ++i) { const int d = d0 + 8 + i; Vt[d * 64 + (kr ^ ((d & 7) * 8))] = x1[i]; }
    }
    __syncthreads();

    float p[4][4];                                 // [col-tile j][row reg r]
#pragma unroll
    for (int j = 0; j < 4; ++j) {
      const int kg = k0 + j * 16 + l15;
      f32x4 s = {};
#pragma unroll
      for (int kh = 0; kh < 2; ++kh) {
        bf16x8 bk = *(const bf16x8*)(QKVP + (size_t)(b * Sc + kg) * 4608 + Hc + h * 64 + kh * 32 + lhi * 8);
        s = __builtin_amdgcn_mfma_f32_16x16x32_bf16(aq[kh], bk, s, 0, 0, 0);
      }
      const int vk = vb[kg];
      const u16* prow = p2cB + (size_t)kg * P2c;
#pragma unroll
      for (int r = 0; r < 4; ++r) {
        const int qg = qrb + lhi * 4 + r;
        const int dlt = qg - kg + 1023;
        const float rel = bf2f(c2pB[(size_t)qg * P2c + cT[dlt]]) + bf2f(prow[pT[dlt]]);
        p[j][r] = vk ? (s[r] + rel) : -1e30f;
      }
    }
    float resc[4];
#pragma unroll
    for (int r = 0; r < 4; ++r) {
      float mx = fmaxf(fmaxf(p[0][r], p[1][r]), fmaxf(p[2][r], p[3][r]));
#pragma unroll
      for (int off = 1; off <= 8; off <<= 1) mx = fmaxf(mx, __shfl_xor(mx, off));
      const float mnew = fmaxf(m_run[r], mx);
      const float gate = mnew > -1e29f ? 1.f : 0.f;  // fully-masked-so-far row -> contribute 0
      const float sc = __expf(m_run[r] - mnew);
      float rs = 0.f;
#pragma unroll
      for (int j = 0; j < 4; ++j) { p[j][r] = __expf(p[j][r] - mnew) * gate; rs += p[j][r]; }
#pragma unroll
      for (int off = 1; off <= 8; off <<= 1) rs += __shfl_xor(rs, off);
      l_run[r] = l_run[r] * sc + rs;
      m_run[r] = mnew;
      resc[r] = sc;
    }
#pragma unroll
    for (int jd = 0; jd < 4; ++jd)
#pragma unroll
      for (int r = 0; r < 4; ++r) o_acc[jd][r] *= resc[r];

    u16* myP = Pl[wid];
#pragma unroll
    for (int j = 0; j < 4; ++j)
#pragma unroll
      for (int r = 0; r < 4; ++r) {
        const int row = lhi * 4 + r, col = j * 16 + l15;
        myP[row * 64 + (col ^ ((row & 7) * 8))] = f2bf(p[j][r]);
      }
#pragma unroll
    for (int jd = 0; jd < 4; ++jd) {
      const int d = jd * 16 + l15;
#pragma unroll
      for (int kh = 0; kh < 2; ++kh) {
        bf16x8 pa = *(const bf16x8*)(myP + l15 * 64 + ((kh * 32 + lhi * 8) ^ ((l15 & 7) * 8)));
        bf16x8 vv = *(const bf16x8*)(Vt  + d * 64   + ((kh * 32 + lhi * 8) ^ ((d   & 7) * 8)));
        o_acc[jd] = __builtin_amdgcn_mfma_f32_16x16x32_bf16(pa, vv, o_acc[jd], 0, 0, 0);
      }
    }
    __syncthreads();
  }

#pragma unroll
  for (int jd = 0; jd < 4; ++jd)
#pragma unroll
    for (int r = 0; r < 4; ++r) {
      const int qg = qrb + lhi * 4 + r;
      const float inv = l_run[r] > 0.f ? 1.f / l_run[r] : 0.f;
      const float o = o_acc[jd][r] * inv * (vb[qg] ? 1.f : 0.f);
      ctx[(size_t)(b * Sc + qg) * Hc + h * 64 + jd * 16 + l15] = f2bf(o);
    }
}

// ---------------- row-wise LayerNorm in-place on d_out ----------------
__global__ __launch_bounds__(256) void ln_kernel(float* __restrict__ io,
    const float* __restrict__ g, const float* __restrict__ bta)
{
  const int row = blockIdx.x;
  float* p = io + (size_t)row * Hc;
  const int tid = threadIdx.x, wid = tid >> 6, lane = tid & 63;
  float v[6];
  float s = 0.f;
#pragma unroll
  for (int j = 0; j < 6; ++j) { v[j] = p[tid + j * 256]; s += v[j]; }
#pragma unroll
  for (int off = 1; off <= 32; off <<= 1) s += __shfl_xor(s, off);
  __shared__ float red[4];
  if (lane == 0) red[wid] = s;
  __syncthreads();
  const float mu = (red[0] + red[1] + red[2] + red[3]) * (1.f / Hc);
  float q = 0.f;
#pragma unroll
  for (int j = 0; j < 6; ++j) { const float d = v[j] - mu; q += d * d; }
#pragma unroll
  for (int off = 1; off <= 32; off <<= 1) q += __shfl_xor(q, off);
  __syncthreads();
  if (lane == 0) red[wid] = q;
  __syncthreads();
  const float rstd = rsqrtf((red[0] + red[1] + red[2] + red[3]) * (1.f / Hc) + 1e-7f);
#pragma unroll
  for (int j = 0; j < 6; ++j) {
    const int c = tid + j * 256;
    p[c] = (v[j] - mu) * rstd * g[c] + bta[c];
  }
}

// ---------------- host launcher ----------------
extern "C" void kernel_launch(void* const* d_in, const int* in_sizes, int n_in,
                              void* d_out, int out_size, void* d_ws, size_t ws_size,
                              hipStream_t stream)
{
  (void)in_sizes; (void)n_in; (void)out_size;
  const float* hidden = (const float*)d_in[0];
  const float* relemb = (const float*)d_in[1];
  const float* Wq = (const float*)d_in[2];
  const float* bq = (const float*)d_in[3];
  const float* Wk = (const float*)d_in[4];
  const float* bk = (const float*)d_in[5];
  const float* Wv = (const float*)d_in[6];
  const float* bv = (const float*)d_in[7];
  const float* Wo = (const float*)d_in[8];
  const float* bo = (const float*)d_in[9];
  const float* lng = (const float*)d_in[10];
  const float* lnb = (const float*)d_in[11];
  const int* am = (const int*)d_in[12];
  const int* rp = (const int*)d_in[13];
  float* out = (float*)d_out;

  char* ws = (char*)d_ws;
  size_t off = 0;
  auto alloc = [&](size_t bytes) { size_t r = off; off += (bytes + 255) & ~(size_t)255; return r; };
  const size_t o_qkvp = alloc((size_t)MA * 4608 * 2);   // 42.5 MB  QKV+pos projections (bf16)
  const size_t o_wt   = alloc((size_t)N3 * Hc * 2);     // 14.2 MB  [Wq;Wk;Wv]^T bf16
  const size_t o_wot  = alloc((size_t)Hc * Hc * 2);     //  4.7 MB  Wo^T bf16
  const size_t o_abig = alloc((size_t)MA * Hc * 2);     // 14.2 MB  [X;rel] bf16 (later aliased by ctx)
  const size_t o_bias = alloc((size_t)N3 * 4);
  const size_t o_valid= alloc((size_t)MX * 4);
  const size_t o_cidx = alloc(2048 * 2);
  const size_t o_pidx = alloc(2048 * 2);
  const size_t fixed  = off;                            // ~75.6 MB
  const size_t o_rel  = off;                            // + chunk*2MB for c2p/p2c

  int c = 96;                                           // bh per chunk: 96,48,24,12,6,3,1
  while (c > 1 && fixed + (size_t)c * 2 * Sc * P2c * 2 > ws_size) c >>= 1;

  u16* QKVP = (u16*)(ws + o_qkvp);
  u16* WT   = (u16*)(ws + o_wt);
  u16* WOT  = (u16*)(ws + o_wot);
  u16* ABIG = (u16*)(ws + o_abig);
  u16* CTX  = (u16*)(ws + o_abig);                      // alias: ABIG dead after gemm<0>
  float* BIAS = (float*)(ws + o_bias);
  int* VALID  = (int*)(ws + o_valid);
  u16* CIDX = (u16*)(ws + o_cidx);
  u16* PIDX = (u16*)(ws + o_pidx);
  u16* C2P  = (u16*)(ws + o_rel);
  u16* P2C  = C2P + (size_t)c * Sc * P2c;

  prep_misc<<<dim3(50), dim3(256), 0, stream>>>(bq, bk, bv, am, rp, BIAS, VALID, CIDX, PIDX);
  cast_x<<<dim3(1728), dim3(256), 0, stream>>>(hidden, relemb, ABIG);
  transpose_cast<<<dim3(48, 48, 4), dim3(32, 8), 0, stream>>>(Wq, Wk, Wv, Wo, WT, WOT);
  gemm128<0><<<dim3(36, 36), dim3(256), 0, stream>>>(ABIG, WT, BIAS, (const float*)nullptr,
                                                     QKVP, (float*)nullptr, 4608);
  for (int base = 0; base < 96; base += c) {
    relmat_kernel<<<dim3(4, 16, c * 2), dim3(256), 0, stream>>>(QKVP, C2P, P2C, base);
    flash_kernel<<<dim3(c * 16), dim3(256), 0, stream>>>(QKVP, C2P, P2C, VALID, CIDX, PIDX,
                                                         CTX, base, c);
  }
  gemm128<1><<<dim3(12, 32), dim3(256), 0, stream>>>(CTX, WOT, bo, hidden,
                                                     (u16*)nullptr, out, Hc);
  ln_kernel<<<dim3(MX), dim3(256), 0, stream>>>(out, lng, lnb);
}